// Round 2
// baseline (4160.804 us; speedup 1.0000x reference)
//
#include <hip/hip_runtime.h>
#include <hip/hip_bf16.h>
#include <math.h>

#define N_NODES 100000
#define DD 128
#define MAXDEG 16
#define HIDW 256
#define NBLOCKS 5
#define NGRAPH 2048
#define CATW 768   // D*(BLOCKS+1)

// ---------- column min over rows (partials) ----------
__global__ __launch_bounds__(256)
void k_colmin_part(const float* __restrict__ h, float* __restrict__ part, int nrows)
{
    int t = threadIdx.x;
    int c = t & 127, half = t >> 7;
    int r0 = blockIdx.x * 256;
    int rend = r0 + 256; if (rend > nrows) rend = nrows;
    float m = INFINITY;
    for (int r = r0 + half; r < rend; r += 2)
        m = fminf(m, h[(size_t)r * DD + c]);
    __shared__ float sm[256];
    sm[t] = m;
    __syncthreads();
    if (half == 0) part[(size_t)blockIdx.x * DD + c] = fminf(sm[c], sm[c + 128]);
}

__global__ void k_colmin_fin(const float* __restrict__ part, float* __restrict__ colmin, int nb)
{
    int c = threadIdx.x; // 128 threads
    float m = INFINITY;
    for (int b = 0; b < nb; ++b) m = fminf(m, part[(size_t)b * DD + c]);
    colmin[c] = m;
}

// ---------- neighbor aggregation: sum + max into fused A (N x 256) ----------
__global__ __launch_bounds__(256)
void k_aggregate(const float* __restrict__ h, const int* __restrict__ nbr,
                 const float* __restrict__ colmin, float* __restrict__ A)
{
    int node = blockIdx.x * 2 + (threadIdx.x >> 7);
    int c = threadIdx.x & 127;
    if (node >= N_NODES) return;
    const int* row = nbr + (size_t)node * MAXDEG;
    float s = 0.f, m = -INFINITY;
    int cnt = 0;
#pragma unroll
    for (int j = 0; j < MAXDEG; ++j) {
        int id = row[j];
        if (id >= 0) {
            float v = h[(size_t)id * DD + c];
            s += v;
            m = fmaxf(m, v);
            ++cnt;
        }
    }
    if (cnt == 0) m = colmin[c];
    A[(size_t)node * (2 * DD) + c] = s;
    A[(size_t)node * (2 * DD) + DD + c] = m;
}

// ---------- tiled fp32 GEMM: C = epi(A(nrows x K) @ W(K x M) + bias) ----------
// epilogue: optional += (1+*eps_ptr)*hres[row][col]; optional relu
__global__ __launch_bounds__(256)
void k_gemm(const float* __restrict__ A, const float* __restrict__ W,
            const float* __restrict__ bias, const float* __restrict__ hres,
            const float* __restrict__ eps_ptr, float* __restrict__ C,
            int nrows, int K, int M, int do_relu)
{
    __shared__ float As[16][132];
    __shared__ float Ws[16][132];
    const int t = threadIdx.x;
    const int tx = t & 15, ty = t >> 4;
    const int rb = blockIdx.x * 128;
    const int cb = blockIdx.y * 128;
    float acc[8][8];
#pragma unroll
    for (int i = 0; i < 8; ++i)
#pragma unroll
        for (int j = 0; j < 8; ++j) acc[i][j] = 0.f;

    const int kq = t & 3;
    const int row0 = t >> 2;
    for (int k0 = 0; k0 < K; k0 += 16) {
#pragma unroll
        for (int rr = 0; rr < 2; ++rr) {
            int r = row0 + rr * 64;
            int gr = rb + r;
            float4 v = make_float4(0.f, 0.f, 0.f, 0.f);
            if (gr < nrows)
                v = *reinterpret_cast<const float4*>(A + (size_t)gr * K + k0 + kq * 4);
            As[kq * 4 + 0][r] = v.x;
            As[kq * 4 + 1][r] = v.y;
            As[kq * 4 + 2][r] = v.z;
            As[kq * 4 + 3][r] = v.w;
        }
#pragma unroll
        for (int wwi = 0; wwi < 2; ++wwi) {
            int idx = t + wwi * 256;
            int kr = idx >> 5;
            int cq = idx & 31;
            float4 v = *reinterpret_cast<const float4*>(W + (size_t)(k0 + kr) * M + cb + cq * 4);
            *reinterpret_cast<float4*>(&Ws[kr][cq * 4]) = v;
        }
        __syncthreads();
#pragma unroll
        for (int kk = 0; kk < 16; ++kk) {
            float4 a0 = *reinterpret_cast<const float4*>(&As[kk][ty * 8]);
            float4 a1 = *reinterpret_cast<const float4*>(&As[kk][ty * 8 + 4]);
            float4 b0 = *reinterpret_cast<const float4*>(&Ws[kk][tx * 4]);
            float4 b1 = *reinterpret_cast<const float4*>(&Ws[kk][64 + tx * 4]);
            float a[8] = {a0.x, a0.y, a0.z, a0.w, a1.x, a1.y, a1.z, a1.w};
            float b[8] = {b0.x, b0.y, b0.z, b0.w, b1.x, b1.y, b1.z, b1.w};
#pragma unroll
            for (int i = 0; i < 8; ++i)
#pragma unroll
                for (int j = 0; j < 8; ++j)
                    acc[i][j] = fmaf(a[i], b[j], acc[i][j]);
        }
        __syncthreads();
    }

    float bl[8];
#pragma unroll
    for (int j = 0; j < 4; ++j) {
        bl[j] = bias[cb + tx * 4 + j];
        bl[4 + j] = bias[cb + 64 + tx * 4 + j];
    }
    float alpha = 0.f;
    if (eps_ptr != nullptr) alpha = 1.f + *eps_ptr;
#pragma unroll
    for (int i = 0; i < 8; ++i) {
        int gr = rb + ty * 8 + i;
        if (gr >= nrows) continue;
        float o[8];
#pragma unroll
        for (int j = 0; j < 8; ++j) o[j] = acc[i][j] + bl[j];
        if (hres != nullptr) {
#pragma unroll
            for (int j = 0; j < 4; ++j) {
                o[j]     += alpha * hres[(size_t)gr * M + cb + tx * 4 + j];
                o[4 + j] += alpha * hres[(size_t)gr * M + cb + 64 + tx * 4 + j];
            }
        }
        if (do_relu) {
#pragma unroll
            for (int j = 0; j < 8; ++j) o[j] = fmaxf(o[j], 0.f);
        }
        float4 o0 = make_float4(o[0], o[1], o[2], o[3]);
        float4 o1 = make_float4(o[4], o[5], o[6], o[7]);
        *reinterpret_cast<float4*>(C + (size_t)gr * M + cb + tx * 4) = o0;
        *reinterpret_cast<float4*>(C + (size_t)gr * M + cb + 64 + tx * 4) = o1;
    }
}

// ---------- BatchNorm stats partials (sum, sumsq per column) ----------
__global__ __launch_bounds__(256)
void k_bn_part(const float* __restrict__ u, float* __restrict__ part, int nrows)
{
    int t = threadIdx.x;
    int c = t & 127, half = t >> 7;
    int r0 = blockIdx.x * 256;
    int rend = r0 + 256; if (rend > nrows) rend = nrows;
    float s1 = 0.f, s2 = 0.f;
    for (int r = r0 + half; r < rend; r += 2) {
        float v = u[(size_t)r * DD + c];
        s1 += v; s2 += v * v;
    }
    __shared__ float sh1[256], sh2[256];
    sh1[t] = s1; sh2[t] = s2;
    __syncthreads();
    if (half == 0) {
        part[(size_t)blockIdx.x * 256 + c]       = sh1[c] + sh1[c + 128];
        part[(size_t)blockIdx.x * 256 + 128 + c] = sh2[c] + sh2[c + 128];
    }
}

__global__ void k_bn_fin(const float* __restrict__ part, int nb, float inv_n,
                         float* __restrict__ mean, float* __restrict__ inv)
{
    int c = threadIdx.x; // 128 threads
    float s1 = 0.f, s2 = 0.f;
    for (int b = 0; b < nb; ++b) {
        s1 += part[(size_t)b * 256 + c];
        s2 += part[(size_t)b * 256 + 128 + c];
    }
    float m = s1 * inv_n;
    float v = s2 * inv_n - m * m;
    mean[c] = m;
    inv[c] = rsqrtf(v + 1e-5f);
}

// ---------- BN apply + h update + segmented scan-add into G ----------
__global__ __launch_bounds__(256)
void k_bn_apply_scan(const float* __restrict__ u, float* __restrict__ h,
                     const float* __restrict__ mean, const float* __restrict__ inv,
                     const float* __restrict__ gam, const float* __restrict__ bet,
                     const int* __restrict__ mem, float* __restrict__ G,
                     int colbase, int nrows)
{
    int t = threadIdx.x;
    int c = t & 127, half = t >> 7;
    int r0 = blockIdx.x * 128;
    int rend = r0 + 128; if (rend > nrows) rend = nrows;
    float mu = mean[c], iv = inv[c], g = gam[c], b = bet[c];
    float accv = 0.f;
    int curg = -1;
    for (int r = r0 + half; r < rend; r += 2) {
        float z = g * (u[(size_t)r * DD + c] - mu) * iv + b;
        h[(size_t)r * DD + c] += z;
        int gg = mem[r];
        if (gg != curg) {
            if (curg >= 0) atomicAdd(&G[(size_t)curg * CATW + colbase + c], accv);
            curg = gg; accv = 0.f;
        }
        accv += z;
    }
    if (curg >= 0) atomicAdd(&G[(size_t)curg * CATW + colbase + c], accv);
}

// ---------- segmented scan-add of x into G cols [0,128) ----------
__global__ __launch_bounds__(256)
void k_scan_x(const float* __restrict__ x, const int* __restrict__ mem,
              float* __restrict__ G, int nrows)
{
    int t = threadIdx.x;
    int c = t & 127, half = t >> 7;
    int r0 = blockIdx.x * 128;
    int rend = r0 + 128; if (rend > nrows) rend = nrows;
    float accv = 0.f;
    int curg = -1;
    for (int r = r0 + half; r < rend; r += 2) {
        float z = x[(size_t)r * DD + c];
        int gg = mem[r];
        if (gg != curg) {
            if (curg >= 0) atomicAdd(&G[(size_t)curg * CATW + c], accv);
            curg = gg; accv = 0.f;
        }
        accv += z;
    }
    if (curg >= 0) atomicAdd(&G[(size_t)curg * CATW + c], accv);
}

// ---------- final BN + dot with dense2 ----------
__global__ __launch_bounds__(256)
void k_final(const float* __restrict__ g1, const float* __restrict__ mean,
             const float* __restrict__ inv, const float* __restrict__ gam,
             const float* __restrict__ bet, const float* __restrict__ W2,
             const float* __restrict__ b2, float* __restrict__ out)
{
    int w = threadIdx.x >> 6, lane = threadIdx.x & 63;
    int row = blockIdx.x * 4 + w;
    float s = 0.f;
#pragma unroll
    for (int q = 0; q < 2; ++q) {
        int c = lane + q * 64;
        float v = gam[c] * (g1[(size_t)row * DD + c] - mean[c]) * inv[c] + bet[c];
        s += v * W2[c];
    }
#pragma unroll
    for (int off = 32; off > 0; off >>= 1) s += __shfl_down(s, off);
    if (lane == 0) out[row] = s + b2[0];
}

extern "C" void kernel_launch(void* const* d_in, const int* in_sizes, int n_in,
                              void* d_out, int out_size, void* d_ws, size_t ws_size,
                              hipStream_t stream)
{
    const float* x       = (const float*)d_in[0];
    const int*   nbr     = (const int*)d_in[1];
    const int*   mem     = (const int*)d_in[2];
    const float* merge_W = (const float*)d_in[3];
    const float* merge_b = (const float*)d_in[4];
    const float* lin1_W  = (const float*)d_in[5];
    const float* lin1_b  = (const float*)d_in[6];
    const float* lin2_W  = (const float*)d_in[7];
    const float* lin2_b  = (const float*)d_in[8];
    const float* bn_g    = (const float*)d_in[9];
    const float* bn_b    = (const float*)d_in[10];
    const float* epsv    = (const float*)d_in[11];
    const float* d0W     = (const float*)d_in[12];
    const float* d0b     = (const float*)d_in[13];
    const float* d1W     = (const float*)d_in[14];
    const float* d1b     = (const float*)d_in[15];
    const float* bn0g    = (const float*)d_in[16];
    const float* bn0b    = (const float*)d_in[17];
    const float* d2W     = (const float*)d_in[18];
    const float* d2b     = (const float*)d_in[19];
    float* out = (float*)d_out;

    float* ws   = (float*)d_ws;
    float* h    = ws;                                  // N*128
    float* Abuf = h + (size_t)N_NODES * DD;            // N*256 (aggr / t)
    float* zb   = Abuf + (size_t)N_NODES * 2 * DD;     // N*128 (z / u)
    float* G    = zb + (size_t)N_NODES * DD;           // 2048*768
    float* g0   = G + (size_t)NGRAPH * CATW;           // 2048*256
    float* g1   = g0 + (size_t)NGRAPH * HIDW;          // 2048*128
    float* part = g1 + (size_t)NGRAPH * DD;            // 391*256
    float* red  = part + (size_t)391 * 256;            // small
    float* colmin = red;
    float* meanp  = red + DD;
    float* invp   = red + 2 * DD;

    const int NBP = 391;      // ceil(100000/256)
    const int NRB = 782;      // ceil(100000/128)

    hipMemcpyAsync(h, x, (size_t)N_NODES * DD * sizeof(float),
                   hipMemcpyDeviceToDevice, stream);
    hipMemsetAsync(G, 0, (size_t)NGRAPH * CATW * sizeof(float), stream);

    k_scan_x<<<NRB, 256, 0, stream>>>(x, mem, G, N_NODES);

    for (int i = 0; i < NBLOCKS; ++i) {
        k_colmin_part<<<NBP, 256, 0, stream>>>(h, part, N_NODES);
        k_colmin_fin<<<1, 128, 0, stream>>>(part, colmin, NBP);
        k_aggregate<<<N_NODES / 2, 256, 0, stream>>>(h, nbr, colmin, Abuf);
        // z = A @ merge_W[i] + merge_b[i] + (1+eps[i])*h
        k_gemm<<<dim3(NRB, 1), 256, 0, stream>>>(Abuf, merge_W + (size_t)i * 2 * DD * DD,
                                                 merge_b + (size_t)i * DD, h, epsv + i,
                                                 zb, N_NODES, 2 * DD, DD, 0);
        // t = relu(z @ lin1_W[i] + lin1_b[i])
        k_gemm<<<dim3(NRB, 2), 256, 0, stream>>>(zb, lin1_W + (size_t)i * DD * HIDW,
                                                 lin1_b + (size_t)i * HIDW, nullptr, nullptr,
                                                 Abuf, N_NODES, DD, HIDW, 1);
        // u = relu(t @ lin2_W[i] + lin2_b[i])
        k_gemm<<<dim3(NRB, 1), 256, 0, stream>>>(Abuf, lin2_W + (size_t)i * HIDW * DD,
                                                 lin2_b + (size_t)i * DD, nullptr, nullptr,
                                                 zb, N_NODES, HIDW, DD, 1);
        k_bn_part<<<NBP, 256, 0, stream>>>(zb, part, N_NODES);
        k_bn_fin<<<1, 128, 0, stream>>>(part, NBP, 1.f / (float)N_NODES, meanp, invp);
        k_bn_apply_scan<<<NRB, 256, 0, stream>>>(zb, h, meanp, invp,
                                                 bn_g + (size_t)i * DD, bn_b + (size_t)i * DD,
                                                 mem, G, (i + 1) * DD, N_NODES);
    }

    // readout MLP
    k_gemm<<<dim3(16, 2), 256, 0, stream>>>(G, d0W, d0b, nullptr, nullptr,
                                            g0, NGRAPH, CATW, HIDW, 1);
    k_gemm<<<dim3(16, 1), 256, 0, stream>>>(g0, d1W, d1b, nullptr, nullptr,
                                            g1, NGRAPH, HIDW, DD, 1);
    k_bn_part<<<8, 256, 0, stream>>>(g1, part, NGRAPH);
    k_bn_fin<<<1, 128, 0, stream>>>(part, 8, 1.f / (float)NGRAPH, meanp, invp);
    k_final<<<NGRAPH / 4, 256, 0, stream>>>(g1, meanp, invp, bn0g, bn0b, d2W, d2b, out);
}

// Round 4
// 2777.417 us; speedup vs baseline: 1.4981x; 1.4981x over previous
//
#include <hip/hip_runtime.h>
#include <hip/hip_bf16.h>
#include <math.h>

#define N_NODES 100000
#define DD 128
#define MAXDEG 16
#define HIDW 256
#define NBLOCKS 5
#define NGRAPH 2048
#define CATW 768   // D*(BLOCKS+1)

typedef __attribute__((ext_vector_type(8))) short short8;
typedef __attribute__((ext_vector_type(4))) float f32x4;

__device__ __forceinline__ float b2f(ushort u) {
    union { unsigned int i; float f; } x; x.i = ((unsigned int)u) << 16; return x.f;
}
__device__ __forceinline__ ushort f2b(float f) {
    unsigned int x = __float_as_uint(f);
    unsigned int r = (x + 0x7fffu + ((x >> 16) & 1u)) >> 16;
    return (ushort)r;
}

// ---------- init: h = x (fp32), hb = bf16(x) ----------
__global__ __launch_bounds__(256)
void k_init(const float* __restrict__ x, float* __restrict__ h, ushort* __restrict__ hb)
{
    size_t i = ((size_t)blockIdx.x * 256 + threadIdx.x) * 4;
    float4 v = *reinterpret_cast<const float4*>(x + i);
    *reinterpret_cast<float4*>(h + i) = v;
    ushort4 u;
    u.x = f2b(v.x); u.y = f2b(v.y); u.z = f2b(v.z); u.w = f2b(v.w);
    *reinterpret_cast<ushort4*>(hb + i) = u;
}

// ---------- batched convert + transpose: src (cnt,K,M) fp32 -> dst (cnt,M,K) bf16 ----------
__global__ __launch_bounds__(256)
void k_convT(const float* __restrict__ src, ushort* __restrict__ dst, int K, int M, int total)
{
    int id = blockIdx.x * 256 + threadIdx.x;
    if (id >= total) return;
    int km = K * M;
    int b = id / km, rem = id - b * km;
    int m = rem / K, k = rem - m * K;
    dst[(size_t)b * km + (size_t)m * K + k] = f2b(src[(size_t)b * km + (size_t)k * M + m]);
}

// ---------- column min over rows of hb (bf16) ----------
__global__ __launch_bounds__(256)
void k_colmin_part_b(const ushort* __restrict__ hb, float* __restrict__ part, int nrows)
{
    int t = threadIdx.x;
    int c = t & 127, half = t >> 7;
    int r0 = blockIdx.x * 256;
    int rend = r0 + 256; if (rend > nrows) rend = nrows;
    float m = INFINITY;
    for (int r = r0 + half; r < rend; r += 2)
        m = fminf(m, b2f(hb[(size_t)r * DD + c]));
    __shared__ float sm[256];
    sm[t] = m;
    __syncthreads();
    if (half == 0) part[(size_t)blockIdx.x * DD + c] = fminf(sm[c], sm[c + 128]);
}

__global__ void k_colmin_fin(const float* __restrict__ part, float* __restrict__ colmin, int nb)
{
    int c = threadIdx.x; // 128 threads
    float m = INFINITY;
    for (int b = 0; b < nb; ++b) m = fminf(m, part[(size_t)b * DD + c]);
    colmin[c] = m;
}

// ---------- aggregation (bf16 in/out): 8 nodes/block, 32 lanes/node, 4 cols/lane ----------
__global__ __launch_bounds__(256)
void k_aggregate_b(const ushort* __restrict__ hb, const int* __restrict__ nbr,
                   const float* __restrict__ colmin, ushort* __restrict__ A)
{
    int t = threadIdx.x;
    int node = blockIdx.x * 8 + (t >> 5);
    int c0 = (t & 31) * 4;
    const int* row = nbr + (size_t)node * MAXDEG;
    float s0 = 0.f, s1 = 0.f, s2 = 0.f, s3 = 0.f;
    float m0 = -INFINITY, m1 = -INFINITY, m2 = -INFINITY, m3 = -INFINITY;
    int cnt = 0;
#pragma unroll
    for (int j = 0; j < MAXDEG; ++j) {
        int id = row[j];
        if (id >= 0) {
            uint2 v = *reinterpret_cast<const uint2*>(hb + (size_t)id * DD + c0);
            float f0 = __uint_as_float(v.x << 16);
            float f1 = __uint_as_float(v.x & 0xffff0000u);
            float f2 = __uint_as_float(v.y << 16);
            float f3 = __uint_as_float(v.y & 0xffff0000u);
            s0 += f0; s1 += f1; s2 += f2; s3 += f3;
            m0 = fmaxf(m0, f0); m1 = fmaxf(m1, f1);
            m2 = fmaxf(m2, f2); m3 = fmaxf(m3, f3);
            ++cnt;
        }
    }
    if (cnt == 0) {
        m0 = colmin[c0]; m1 = colmin[c0 + 1]; m2 = colmin[c0 + 2]; m3 = colmin[c0 + 3];
    }
    ushort4 us, um;
    us.x = f2b(s0); us.y = f2b(s1); us.z = f2b(s2); us.w = f2b(s3);
    um.x = f2b(m0); um.y = f2b(m1); um.z = f2b(m2); um.w = f2b(m3);
    *reinterpret_cast<ushort4*>(A + (size_t)node * (2 * DD) + c0) = us;
    *reinterpret_cast<ushort4*>(A + (size_t)node * (2 * DD) + DD + c0) = um;
}

// ---------- bf16 MFMA GEMM: C = epi(A(nrows x K) @ Wt(M x K)^T + bias) ----------
// A row-major bf16, Wt row-major bf16 (output-col major). 128x128 tile, BK=64.
// epilogue: optional += (1+*eps_ptr)*hres (fp32); optional relu; out bf16 or fp32.
__global__ __launch_bounds__(256)
void k_gemm_mfma(const ushort* __restrict__ Ag, const ushort* __restrict__ Wt,
                 const float* __restrict__ bias, const float* __restrict__ hres,
                 const float* __restrict__ eps_ptr, void* __restrict__ C,
                 int nrows, int K, int M, int relu, int out_f32)
{
    __shared__ __align__(16) ushort As[128 * 64];
    __shared__ __align__(16) ushort Bs[128 * 64];
    const int t = threadIdx.x;
    const int lane = t & 63, wave = t >> 6;
    const int wr = wave >> 1, wc = wave & 1;
    const int lr = lane & 15, lk = (lane >> 4) << 3;
    const int rb = blockIdx.x * 128;
    const int cb = blockIdx.y * 128;

    f32x4 acc[4][4];
#pragma unroll
    for (int m = 0; m < 4; ++m)
#pragma unroll
        for (int n = 0; n < 4; ++n) acc[m][n] = (f32x4)(0.f);

    for (int k0 = 0; k0 < K; k0 += 64) {
        // stage A tile (128 rows x 64 k) with row-XOR swizzle
#pragma unroll
        for (int p = 0; p < 4; ++p) {
            int idx = p * 256 + t, row = idx >> 3, ch = idx & 7;
            int gr = rb + row;
            short8 v = {};
            if (gr < nrows)
                v = *reinterpret_cast<const short8*>(Ag + (size_t)gr * K + k0 + ch * 8);
            int byte = (row << 7) | (ch << 4);
            byte ^= (row & 7) << 4;
            *reinterpret_cast<short8*>(reinterpret_cast<char*>(As) + byte) = v;
        }
        // stage B tile (128 output-cols x 64 k)
#pragma unroll
        for (int p = 0; p < 4; ++p) {
            int idx = p * 256 + t, row = idx >> 3, ch = idx & 7;
            short8 v = *reinterpret_cast<const short8*>(Wt + (size_t)(cb + row) * K + k0 + ch * 8);
            int byte = (row << 7) | (ch << 4);
            byte ^= (row & 7) << 4;
            *reinterpret_cast<short8*>(reinterpret_cast<char*>(Bs) + byte) = v;
        }
        __syncthreads();
#pragma unroll
        for (int k32 = 0; k32 < 2; ++k32) {
            short8 af[4], bq[4];
#pragma unroll
            for (int m = 0; m < 4; ++m) {
                int row = wr * 64 + m * 16 + lr;
                int byte = (row << 7) | ((k32 * 32 + lk) << 1);
                byte ^= (row & 7) << 4;
                af[m] = *reinterpret_cast<const short8*>(reinterpret_cast<const char*>(As) + byte);
            }
#pragma unroll
            for (int n = 0; n < 4; ++n) {
                int col = wc * 64 + n * 16 + lr;
                int byte = (col << 7) | ((k32 * 32 + lk) << 1);
                byte ^= (col & 7) << 4;
                bq[n] = *reinterpret_cast<const short8*>(reinterpret_cast<const char*>(Bs) + byte);
            }
#pragma unroll
            for (int m = 0; m < 4; ++m)
#pragma unroll
                for (int n = 0; n < 4; ++n)
                    acc[m][n] = __builtin_amdgcn_mfma_f32_16x16x32_bf16(af[m], bq[n], acc[m][n], 0, 0, 0);
        }
        __syncthreads();
    }

    float alpha = 0.f;
    if (eps_ptr != nullptr) alpha = 1.f + *eps_ptr;
#pragma unroll
    for (int m = 0; m < 4; ++m) {
#pragma unroll
        for (int j = 0; j < 4; ++j) {
            int grow = rb + wr * 64 + m * 16 + (lane >> 4) * 4 + j;
            if (grow >= nrows) continue;
#pragma unroll
            for (int n = 0; n < 4; ++n) {
                int gcol = cb + wc * 64 + n * 16 + lr;
                float o = acc[m][n][j] + bias[gcol];
                if (hres != nullptr) o += alpha * hres[(size_t)grow * M + gcol];
                if (relu) o = fmaxf(o, 0.f);
                if (out_f32) reinterpret_cast<float*>(C)[(size_t)grow * M + gcol] = o;
                else reinterpret_cast<ushort*>(C)[(size_t)grow * M + gcol] = f2b(o);
            }
        }
    }
}

// ---------- tiled fp32 GEMM (readout path): C = epi(A(nrows x K) @ W(K x M) + bias) ----------
__global__ __launch_bounds__(256)
void k_gemm(const float* __restrict__ A, const float* __restrict__ W,
            const float* __restrict__ bias, float* __restrict__ C,
            int nrows, int K, int M, int do_relu)
{
    __shared__ float As[16][132];
    __shared__ float Ws[16][132];
    const int t = threadIdx.x;
    const int tx = t & 15, ty = t >> 4;
    const int rb = blockIdx.x * 128;
    const int cb = blockIdx.y * 128;
    float acc[8][8];
#pragma unroll
    for (int i = 0; i < 8; ++i)
#pragma unroll
        for (int j = 0; j < 8; ++j) acc[i][j] = 0.f;

    const int kq = t & 3;
    const int row0 = t >> 2;
    for (int k0 = 0; k0 < K; k0 += 16) {
#pragma unroll
        for (int rr = 0; rr < 2; ++rr) {
            int r = row0 + rr * 64;
            int gr = rb + r;
            float4 v = make_float4(0.f, 0.f, 0.f, 0.f);
            if (gr < nrows)
                v = *reinterpret_cast<const float4*>(A + (size_t)gr * K + k0 + kq * 4);
            As[kq * 4 + 0][r] = v.x;
            As[kq * 4 + 1][r] = v.y;
            As[kq * 4 + 2][r] = v.z;
            As[kq * 4 + 3][r] = v.w;
        }
#pragma unroll
        for (int wwi = 0; wwi < 2; ++wwi) {
            int idx = t + wwi * 256;
            int kr = idx >> 5;
            int cq = idx & 31;
            float4 v = *reinterpret_cast<const float4*>(W + (size_t)(k0 + kr) * M + cb + cq * 4);
            *reinterpret_cast<float4*>(&Ws[kr][cq * 4]) = v;
        }
        __syncthreads();
#pragma unroll
        for (int kk = 0; kk < 16; ++kk) {
            float4 a0 = *reinterpret_cast<const float4*>(&As[kk][ty * 8]);
            float4 a1 = *reinterpret_cast<const float4*>(&As[kk][ty * 8 + 4]);
            float4 b0 = *reinterpret_cast<const float4*>(&Ws[kk][tx * 4]);
            float4 b1 = *reinterpret_cast<const float4*>(&Ws[kk][64 + tx * 4]);
            float a[8] = {a0.x, a0.y, a0.z, a0.w, a1.x, a1.y, a1.z, a1.w};
            float b[8] = {b0.x, b0.y, b0.z, b0.w, b1.x, b1.y, b1.z, b1.w};
#pragma unroll
            for (int i = 0; i < 8; ++i)
#pragma unroll
                for (int j = 0; j < 8; ++j)
                    acc[i][j] = fmaf(a[i], b[j], acc[i][j]);
        }
        __syncthreads();
    }

    float bl[8];
#pragma unroll
    for (int j = 0; j < 4; ++j) {
        bl[j] = bias[cb + tx * 4 + j];
        bl[4 + j] = bias[cb + 64 + tx * 4 + j];
    }
#pragma unroll
    for (int i = 0; i < 8; ++i) {
        int gr = rb + ty * 8 + i;
        if (gr >= nrows) continue;
        float o[8];
#pragma unroll
        for (int j = 0; j < 8; ++j) o[j] = acc[i][j] + bl[j];
        if (do_relu) {
#pragma unroll
            for (int j = 0; j < 8; ++j) o[j] = fmaxf(o[j], 0.f);
        }
        float4 o0 = make_float4(o[0], o[1], o[2], o[3]);
        float4 o1 = make_float4(o[4], o[5], o[6], o[7]);
        *reinterpret_cast<float4*>(C + (size_t)gr * M + cb + tx * 4) = o0;
        *reinterpret_cast<float4*>(C + (size_t)gr * M + cb + 64 + tx * 4) = o1;
    }
}

// ---------- BN stats partials from fp32 u ----------
__global__ __launch_bounds__(256)
void k_bn_part(const float* __restrict__ u, float* __restrict__ part, int nrows)
{
    int t = threadIdx.x;
    int c = t & 127, half = t >> 7;
    int r0 = blockIdx.x * 256;
    int rend = r0 + 256; if (rend > nrows) rend = nrows;
    float s1 = 0.f, s2 = 0.f;
    for (int r = r0 + half; r < rend; r += 2) {
        float v = u[(size_t)r * DD + c];
        s1 += v; s2 += v * v;
    }
    __shared__ float sh1[256], sh2[256];
    sh1[t] = s1; sh2[t] = s2;
    __syncthreads();
    if (half == 0) {
        part[(size_t)blockIdx.x * 256 + c]       = sh1[c] + sh1[c + 128];
        part[(size_t)blockIdx.x * 256 + 128 + c] = sh2[c] + sh2[c + 128];
    }
}

__global__ void k_bn_fin(const float* __restrict__ part, int nb, float inv_n,
                         float* __restrict__ mean, float* __restrict__ inv)
{
    int c = threadIdx.x; // 128 threads
    float s1 = 0.f, s2 = 0.f;
    for (int b = 0; b < nb; ++b) {
        s1 += part[(size_t)b * 256 + c];
        s2 += part[(size_t)b * 256 + 128 + c];
    }
    float m = s1 * inv_n;
    float v = s2 * inv_n - m * m;
    mean[c] = m;
    inv[c] = rsqrtf(v + 1e-5f);
}

// ---------- BN apply (u fp32) + h fp32 update + hb bf16 mirror + segmented scan into G ----------
__global__ __launch_bounds__(256)
void k_bn_apply_scan(const float* __restrict__ u, float* __restrict__ h,
                     ushort* __restrict__ hb,
                     const float* __restrict__ mean, const float* __restrict__ inv,
                     const float* __restrict__ gam, const float* __restrict__ bet,
                     const int* __restrict__ mem, float* __restrict__ G,
                     int colbase, int nrows)
{
    int t = threadIdx.x;
    int c = t & 127, half = t >> 7;
    int r0 = blockIdx.x * 128;
    int rend = r0 + 128; if (rend > nrows) rend = nrows;
    float mu = mean[c], iv = inv[c], g = gam[c], b = bet[c];
    float accv = 0.f;
    int curg = -1;
    for (int r = r0 + half; r < rend; r += 2) {
        float z = g * (u[(size_t)r * DD + c] - mu) * iv + b;
        float hn = h[(size_t)r * DD + c] + z;
        h[(size_t)r * DD + c] = hn;
        hb[(size_t)r * DD + c] = f2b(hn);
        int gg = mem[r];
        if (gg != curg) {
            if (curg >= 0) atomicAdd(&G[(size_t)curg * CATW + colbase + c], accv);
            curg = gg; accv = 0.f;
        }
        accv += z;
    }
    if (curg >= 0) atomicAdd(&G[(size_t)curg * CATW + colbase + c], accv);
}

// ---------- segmented scan-add of x (fp32) into G cols [0,128) ----------
__global__ __launch_bounds__(256)
void k_scan_x(const float* __restrict__ x, const int* __restrict__ mem,
              float* __restrict__ G, int nrows)
{
    int t = threadIdx.x;
    int c = t & 127, half = t >> 7;
    int r0 = blockIdx.x * 128;
    int rend = r0 + 128; if (rend > nrows) rend = nrows;
    float accv = 0.f;
    int curg = -1;
    for (int r = r0 + half; r < rend; r += 2) {
        float z = x[(size_t)r * DD + c];
        int gg = mem[r];
        if (gg != curg) {
            if (curg >= 0) atomicAdd(&G[(size_t)curg * CATW + c], accv);
            curg = gg; accv = 0.f;
        }
        accv += z;
    }
    if (curg >= 0) atomicAdd(&G[(size_t)curg * CATW + c], accv);
}

// ---------- final BN + dot with dense2 ----------
__global__ __launch_bounds__(256)
void k_final(const float* __restrict__ g1, const float* __restrict__ mean,
             const float* __restrict__ inv, const float* __restrict__ gam,
             const float* __restrict__ bet, const float* __restrict__ W2,
             const float* __restrict__ b2, float* __restrict__ out)
{
    int w = threadIdx.x >> 6, lane = threadIdx.x & 63;
    int row = blockIdx.x * 4 + w;
    float s = 0.f;
#pragma unroll
    for (int q = 0; q < 2; ++q) {
        int c = lane + q * 64;
        float v = gam[c] * (g1[(size_t)row * DD + c] - mean[c]) * inv[c] + bet[c];
        s += v * W2[c];
    }
#pragma unroll
    for (int off = 32; off > 0; off >>= 1) s += __shfl_down(s, off);
    if (lane == 0) out[row] = s + b2[0];
}

extern "C" void kernel_launch(void* const* d_in, const int* in_sizes, int n_in,
                              void* d_out, int out_size, void* d_ws, size_t ws_size,
                              hipStream_t stream)
{
    const float* x       = (const float*)d_in[0];
    const int*   nbr     = (const int*)d_in[1];
    const int*   mem     = (const int*)d_in[2];
    const float* merge_W = (const float*)d_in[3];
    const float* merge_b = (const float*)d_in[4];
    const float* lin1_W  = (const float*)d_in[5];
    const float* lin1_b  = (const float*)d_in[6];
    const float* lin2_W  = (const float*)d_in[7];
    const float* lin2_b  = (const float*)d_in[8];
    const float* bn_g    = (const float*)d_in[9];
    const float* bn_b    = (const float*)d_in[10];
    const float* epsv    = (const float*)d_in[11];
    const float* d0W     = (const float*)d_in[12];
    const float* d0b     = (const float*)d_in[13];
    const float* d1W     = (const float*)d_in[14];
    const float* d1b     = (const float*)d_in[15];
    const float* bn0g    = (const float*)d_in[16];
    const float* bn0b    = (const float*)d_in[17];
    const float* d2W     = (const float*)d_in[18];
    const float* d2b     = (const float*)d_in[19];
    float* out = (float*)d_out;

    // ---- workspace carve (256B aligned chunks) ----
    char* p = (char*)d_ws;
    auto alloc = [&](size_t bytes) { char* r = p; p += (bytes + 255) & ~(size_t)255; return r; };
    float*  h     = (float*)alloc((size_t)N_NODES * DD * 4);        // fp32 master h
    ushort* hb    = (ushort*)alloc((size_t)N_NODES * DD * 2);       // bf16 mirror
    ushort* Abuf  = (ushort*)alloc((size_t)N_NODES * 2 * DD * 2);   // aggr A / t (N x 256 bf16)
    ushort* zbb   = (ushort*)alloc((size_t)N_NODES * DD * 2);       // z (merge out, bf16)
    float*  uf    = (float*)alloc((size_t)N_NODES * DD * 4);        // u (lin2 out, fp32)
    float*  G     = (float*)alloc((size_t)NGRAPH * CATW * 4);
    float*  g0    = (float*)alloc((size_t)NGRAPH * HIDW * 4);
    float*  g1    = (float*)alloc((size_t)NGRAPH * DD * 4);
    float*  part  = (float*)alloc((size_t)391 * 256 * 4);
    float*  red   = (float*)alloc(1024 * 4);
    ushort* mergeT = (ushort*)alloc((size_t)NBLOCKS * 2 * DD * DD * 2);   // 5 x (128 x 256)
    ushort* lin1T  = (ushort*)alloc((size_t)NBLOCKS * DD * HIDW * 2);     // 5 x (256 x 128)
    ushort* lin2T  = (ushort*)alloc((size_t)NBLOCKS * HIDW * DD * 2);     // 5 x (128 x 256)
    float* colmin = red;
    float* meanp  = red + DD;
    float* invp   = red + 2 * DD;

    const int NBP = 391;      // ceil(100000/256)
    const int NRB = 782;      // ceil(100000/128)

    k_init<<<12500, 256, 0, stream>>>(x, h, hb);
    {   // weight convert + transpose (fp32 (K,M) -> bf16 (M,K)) — node-level GEMMs only
        int tm = NBLOCKS * 2 * DD * DD;   // 163840
        k_convT<<<(tm + 255) / 256, 256, 0, stream>>>(merge_W, mergeT, 2 * DD, DD, tm);
        int t1 = NBLOCKS * DD * HIDW;     // 163840
        k_convT<<<(t1 + 255) / 256, 256, 0, stream>>>(lin1_W, lin1T, DD, HIDW, t1);
        int t2 = NBLOCKS * HIDW * DD;     // 163840
        k_convT<<<(t2 + 255) / 256, 256, 0, stream>>>(lin2_W, lin2T, HIDW, DD, t2);
    }
    hipMemsetAsync(G, 0, (size_t)NGRAPH * CATW * sizeof(float), stream);

    k_scan_x<<<NRB, 256, 0, stream>>>(x, mem, G, N_NODES);

    for (int i = 0; i < NBLOCKS; ++i) {
        k_colmin_part_b<<<NBP, 256, 0, stream>>>(hb, part, N_NODES);
        k_colmin_fin<<<1, 128, 0, stream>>>(part, colmin, NBP);
        k_aggregate_b<<<N_NODES / 8, 256, 0, stream>>>(hb, nbr, colmin, Abuf);
        // z = A @ merge_W[i] + b + (1+eps)*h   (out bf16)
        k_gemm_mfma<<<dim3(NRB, 1), 256, 0, stream>>>(
            Abuf, mergeT + (size_t)i * 2 * DD * DD, merge_b + (size_t)i * DD,
            h, epsv + i, zbb, N_NODES, 2 * DD, DD, 0, 0);
        // t = relu(z @ lin1_W[i] + b)   (out bf16)
        k_gemm_mfma<<<dim3(NRB, 2), 256, 0, stream>>>(
            zbb, lin1T + (size_t)i * DD * HIDW, lin1_b + (size_t)i * HIDW,
            nullptr, nullptr, Abuf, N_NODES, DD, HIDW, 1, 0);
        // u = relu(t @ lin2_W[i] + b)   (out fp32 — feeds BN exactly)
        k_gemm_mfma<<<dim3(NRB, 1), 256, 0, stream>>>(
            Abuf, lin2T + (size_t)i * HIDW * DD, lin2_b + (size_t)i * DD,
            nullptr, nullptr, uf, N_NODES, HIDW, DD, 1, 1);
        k_bn_part<<<NBP, 256, 0, stream>>>(uf, part, N_NODES);
        k_bn_fin<<<1, 128, 0, stream>>>(part, NBP, 1.f / (float)N_NODES, meanp, invp);
        k_bn_apply_scan<<<NRB, 256, 0, stream>>>(uf, h, hb, meanp, invp,
                                                 bn_g + (size_t)i * DD, bn_b + (size_t)i * DD,
                                                 mem, G, (i + 1) * DD, N_NODES);
    }

    // readout MLP — fp32 end-to-end (tiny: ~1 GFLOP)
    k_gemm<<<dim3(16, 2), 256, 0, stream>>>(G, d0W, d0b, g0, NGRAPH, CATW, HIDW, 1);
    k_gemm<<<dim3(16, 1), 256, 0, stream>>>(g0, d1W, d1b, g1, NGRAPH, HIDW, DD, 1);
    k_bn_part<<<8, 256, 0, stream>>>(g1, part, NGRAPH);
    k_bn_fin<<<1, 128, 0, stream>>>(part, 8, 1.f / (float)NGRAPH, meanp, invp);
    k_final<<<NGRAPH / 4, 256, 0, stream>>>(g1, meanp, invp, bn0g, bn0b, d2W, d2b, out);
}

// Round 5
// 1616.715 us; speedup vs baseline: 2.5736x; 1.7179x over previous
//
#include <hip/hip_runtime.h>
#include <hip/hip_bf16.h>
#include <math.h>

#define N_NODES 100000
#define DD 128
#define MAXDEG 16
#define HIDW 256
#define NBLOCKS 5
#define NGRAPH 2048
#define CATW 768   // D*(BLOCKS+1)

typedef __attribute__((ext_vector_type(8))) short short8;
typedef __attribute__((ext_vector_type(4))) float f32x4;

__device__ __forceinline__ float b2f(ushort u) {
    union { unsigned int i; float f; } x; x.i = ((unsigned int)u) << 16; return x.f;
}
__device__ __forceinline__ ushort f2b(float f) {
    unsigned int x = __float_as_uint(f);
    unsigned int r = (x + 0x7fffu + ((x >> 16) & 1u)) >> 16;
    return (ushort)r;
}
// order-preserving float<->uint for atomicMin
__device__ __forceinline__ unsigned int encf(float f) {
    unsigned int b = __float_as_uint(f);
    return (b & 0x80000000u) ? ~b : (b | 0x80000000u);
}
__device__ __forceinline__ float decf(unsigned int e) {
    return __uint_as_float((e & 0x80000000u) ? (e & 0x7fffffffu) : ~e);
}

// ---------- init: h = x (fp32), hb = bf16(x) ----------
__global__ __launch_bounds__(256)
void k_init(const float* __restrict__ x, float* __restrict__ h, ushort* __restrict__ hb)
{
    size_t i = ((size_t)blockIdx.x * 256 + threadIdx.x) * 4;
    float4 v = *reinterpret_cast<const float4*>(x + i);
    *reinterpret_cast<float4*>(h + i) = v;
    ushort4 u;
    u.x = f2b(v.x); u.y = f2b(v.y); u.z = f2b(v.z); u.w = f2b(v.w);
    *reinterpret_cast<ushort4*>(hb + i) = u;
}

// ---------- setup: colmin bufs to +inf(enc), bn accumulators to 0 ----------
__global__ void k_setup(unsigned int* __restrict__ cmin, float* __restrict__ bnacc)
{
    int t = threadIdx.x;
    for (int i = t; i < 6 * DD; i += 256) cmin[i] = 0xFF800000u;  // enc(+inf)
    for (int i = t; i < NBLOCKS * 2 * DD; i += 256) bnacc[i] = 0.f;
}

// ---------- batched convert + transpose: src (cnt,K,M) fp32 -> dst (cnt,M,K) bf16 ----------
__global__ __launch_bounds__(256)
void k_convT(const float* __restrict__ src, ushort* __restrict__ dst, int K, int M, int total)
{
    int id = blockIdx.x * 256 + threadIdx.x;
    if (id >= total) return;
    int km = K * M;
    int b = id / km, rem = id - b * km;
    int m = rem / K, k = rem - m * K;
    dst[(size_t)b * km + (size_t)m * K + k] = f2b(src[(size_t)b * km + (size_t)k * M + m]);
}

// ---------- column min over rows of x (fp32, startup only) ----------
__global__ __launch_bounds__(256)
void k_colmin_part(const float* __restrict__ h, float* __restrict__ part, int nrows)
{
    int t = threadIdx.x;
    int c = t & 127, half = t >> 7;
    int r0 = blockIdx.x * 256;
    int rend = r0 + 256; if (rend > nrows) rend = nrows;
    float m = INFINITY;
    for (int r = r0 + half; r < rend; r += 2)
        m = fminf(m, h[(size_t)r * DD + c]);
    __shared__ float sm[256];
    sm[t] = m;
    __syncthreads();
    if (half == 0) part[(size_t)blockIdx.x * DD + c] = fminf(sm[c], sm[c + 128]);
}

__global__ void k_colmin_fin(const float* __restrict__ part, unsigned int* __restrict__ colmin, int nb)
{
    int c = threadIdx.x; // 128 threads
    float m = INFINITY;
    for (int b = 0; b < nb; ++b) m = fminf(m, part[(size_t)b * DD + c]);
    colmin[c] = encf(m);
}

// ---------- aggregation (bf16): 8 nodes/block, 32 lanes/node, 4 cols/lane ----------
__global__ __launch_bounds__(256)
void k_aggregate_b(const ushort* __restrict__ hb, const int* __restrict__ nbr,
                   const unsigned int* __restrict__ cmin, ushort* __restrict__ A)
{
    int t = threadIdx.x;
    int node = blockIdx.x * 8 + (t >> 5);
    int c0 = (t & 31) * 4;
    const int* row = nbr + (size_t)node * MAXDEG;
    float s0 = 0.f, s1 = 0.f, s2 = 0.f, s3 = 0.f;
    float m0 = -INFINITY, m1 = -INFINITY, m2 = -INFINITY, m3 = -INFINITY;
    int cnt = 0;
#pragma unroll
    for (int j = 0; j < MAXDEG; ++j) {
        int id = row[j];
        if (id >= 0) {
            uint2 v = *reinterpret_cast<const uint2*>(hb + (size_t)id * DD + c0);
            float f0 = __uint_as_float(v.x << 16);
            float f1 = __uint_as_float(v.x & 0xffff0000u);
            float f2 = __uint_as_float(v.y << 16);
            float f3 = __uint_as_float(v.y & 0xffff0000u);
            s0 += f0; s1 += f1; s2 += f2; s3 += f3;
            m0 = fmaxf(m0, f0); m1 = fmaxf(m1, f1);
            m2 = fmaxf(m2, f2); m3 = fmaxf(m3, f3);
            ++cnt;
        }
    }
    if (cnt == 0) {
        m0 = decf(cmin[c0]); m1 = decf(cmin[c0 + 1]);
        m2 = decf(cmin[c0 + 2]); m3 = decf(cmin[c0 + 3]);
    }
    ushort4 us, um;
    us.x = f2b(s0); us.y = f2b(s1); us.z = f2b(s2); us.w = f2b(s3);
    um.x = f2b(m0); um.y = f2b(m1); um.z = f2b(m2); um.w = f2b(m3);
    *reinterpret_cast<ushort4*>(A + (size_t)node * (2 * DD) + c0) = us;
    *reinterpret_cast<ushort4*>(A + (size_t)node * (2 * DD) + DD + c0) = um;
}

// ---------- fused per-block MLP: z=Ag@mW^T+(1+eps)h+mb; t=relu(z@w1^T+b1);
//            u=relu(t@w2^T+b2) -> uf, BN partial sums via atomics ----------
// 64-row tile, 4 waves, LDS: As 8K | Bs 16K | Zs 16K | Ts 32K = 72KB
__global__ __launch_bounds__(256, 2)
void k_fused_mlp(const ushort* __restrict__ Ag, const float* __restrict__ h,
                 const ushort* __restrict__ mW, const ushort* __restrict__ w1,
                 const ushort* __restrict__ w2, const float* __restrict__ mb,
                 const float* __restrict__ b1, const float* __restrict__ b2,
                 const float* __restrict__ eps_ptr, float* __restrict__ uf,
                 float* __restrict__ bnacc)
{
    __shared__ __align__(16) char pool[72 * 1024];
    char* As = pool;                 // 8KB  (phase A input staging)
    char* Bs = pool + 8 * 1024;      // 16KB (weight staging, all phases)
    char* Zs = pool + 24 * 1024;     // 16KB z tile bf16 64x128
    char* Ts = pool + 40 * 1024;     // 32KB t tile bf16 64x256
    float* s1 = reinterpret_cast<float*>(pool);         // reuse As region at end
    float* s2 = reinterpret_cast<float*>(pool) + 128;

    const int t = threadIdx.x;
    const int lane = t & 63, wave = t >> 6;
    const int wr = wave >> 1, wc = wave & 1;
    const int lr = lane & 15;
    const int lkb = (lane >> 4) << 4;        // k-byte base within 32k chunk: 0,16,32,48
    const int rb = blockIdx.x * 64;

    // ---------------- phase A: z = Ag(64x256) @ mW^T -> 64x128 ----------------
    f32x4 acc[2][4];
#pragma unroll
    for (int m = 0; m < 2; ++m)
#pragma unroll
        for (int n = 0; n < 4; ++n) acc[m][n] = (f32x4)(0.f);

    for (int k0 = 0; k0 < 256; k0 += 64) {
#pragma unroll
        for (int p = 0; p < 2; ++p) {          // As: 64 rows x 64 k
            int idx = p * 256 + t, row = idx >> 3, ch = idx & 7;
            int gr = rb + row;
            short8 v = {};
            if (gr < N_NODES)
                v = *reinterpret_cast<const short8*>(Ag + (size_t)gr * 256 + k0 + ch * 8);
            int byte = (row << 7) | (ch << 4); byte ^= (row & 7) << 4;
            *reinterpret_cast<short8*>(As + byte) = v;
        }
#pragma unroll
        for (int p = 0; p < 4; ++p) {          // Bs: 128 wrows x 64 k
            int idx = p * 256 + t, row = idx >> 3, ch = idx & 7;
            short8 v = *reinterpret_cast<const short8*>(mW + (size_t)row * 256 + k0 + ch * 8);
            int byte = (row << 7) | (ch << 4); byte ^= (row & 7) << 4;
            *reinterpret_cast<short8*>(Bs + byte) = v;
        }
        __syncthreads();
#pragma unroll
        for (int k32 = 0; k32 < 2; ++k32) {
            short8 af[2], bq[4];
#pragma unroll
            for (int m = 0; m < 2; ++m) {
                int row = wr * 32 + m * 16 + lr;
                int byte = (row << 7) | (k32 * 64 + lkb); byte ^= (row & 7) << 4;
                af[m] = *reinterpret_cast<const short8*>(As + byte);
            }
#pragma unroll
            for (int n = 0; n < 4; ++n) {
                int col = wc * 64 + n * 16 + lr;
                int byte = (col << 7) | (k32 * 64 + lkb); byte ^= (col & 7) << 4;
                bq[n] = *reinterpret_cast<const short8*>(Bs + byte);
            }
#pragma unroll
            for (int m = 0; m < 2; ++m)
#pragma unroll
                for (int n = 0; n < 4; ++n)
                    acc[m][n] = __builtin_amdgcn_mfma_f32_16x16x32_bf16(af[m], bq[n], acc[m][n], 0, 0, 0);
        }
        __syncthreads();
    }
    {   // epilogue A -> Zs (bf16, swizzled)
        float alpha = 1.f + *eps_ptr;
#pragma unroll
        for (int m = 0; m < 2; ++m)
#pragma unroll
            for (int j = 0; j < 4; ++j) {
                int lrow = wr * 32 + m * 16 + (lane >> 4) * 4 + j;
                int grow = rb + lrow;
#pragma unroll
                for (int n = 0; n < 4; ++n) {
                    int col = wc * 64 + n * 16 + lr;
                    float z = acc[m][n][j] + mb[col];
                    if (grow < N_NODES) z += alpha * h[(size_t)grow * DD + col];
                    int byte = (lrow << 8) | (col << 1); byte ^= (lrow & 7) << 4;
                    *reinterpret_cast<ushort*>(Zs + byte) = f2b(z);
                }
            }
    }
    __syncthreads();

    // ---------------- phase B: t = relu(z(64x128) @ w1^T) -> 64x256 ----------------
    f32x4 acb[2][8];
#pragma unroll
    for (int m = 0; m < 2; ++m)
#pragma unroll
        for (int n = 0; n < 8; ++n) acb[m][n] = (f32x4)(0.f);

    for (int kc = 0; kc < 4; ++kc) {           // K=128 in chunks of 32
#pragma unroll
        for (int p = 0; p < 4; ++p) {          // Bs: 256 wrows x 32 k
            int idx = p * 256 + t, row = idx >> 2, ch = idx & 3;
            short8 v = *reinterpret_cast<const short8*>(w1 + (size_t)row * 128 + kc * 32 + ch * 8);
            int byte = (row << 6) | (ch << 4); byte ^= (row & 3) << 4;
            *reinterpret_cast<short8*>(Bs + byte) = v;
        }
        __syncthreads();
        short8 af[2];
#pragma unroll
        for (int m = 0; m < 2; ++m) {
            int row = wr * 32 + m * 16 + lr;
            int byte = (row << 8) | (kc * 64 + lkb); byte ^= (row & 7) << 4;
            af[m] = *reinterpret_cast<const short8*>(Zs + byte);
        }
#pragma unroll
        for (int nh = 0; nh < 2; ++nh) {
            short8 bq[4];
#pragma unroll
            for (int q = 0; q < 4; ++q) {
                int wrow = wc * 128 + nh * 64 + q * 16 + lr;
                int byte = (wrow << 6) | lkb; byte ^= (wrow & 3) << 4;
                bq[q] = *reinterpret_cast<const short8*>(Bs + byte);
            }
#pragma unroll
            for (int m = 0; m < 2; ++m)
#pragma unroll
                for (int q = 0; q < 4; ++q)
                    acb[m][nh * 4 + q] = __builtin_amdgcn_mfma_f32_16x16x32_bf16(af[m], bq[q], acb[m][nh * 4 + q], 0, 0, 0);
        }
        __syncthreads();
    }
    {   // epilogue B -> Ts (bf16, swizzled)
#pragma unroll
        for (int m = 0; m < 2; ++m)
#pragma unroll
            for (int j = 0; j < 4; ++j) {
                int lrow = wr * 32 + m * 16 + (lane >> 4) * 4 + j;
#pragma unroll
                for (int nn = 0; nn < 8; ++nn) {
                    int col = wc * 128 + nn * 16 + lr;
                    float tv = fmaxf(acb[m][nn][j] + b1[col], 0.f);
                    int byte = (lrow << 9) | (col << 1); byte ^= (lrow & 7) << 4;
                    *reinterpret_cast<ushort*>(Ts + byte) = f2b(tv);
                }
            }
    }
    __syncthreads();

    // ---------------- phase C: u = relu(t(64x256) @ w2^T) -> 64x128 ----------------
    f32x4 acu[2][4];
#pragma unroll
    for (int m = 0; m < 2; ++m)
#pragma unroll
        for (int n = 0; n < 4; ++n) acu[m][n] = (f32x4)(0.f);

    for (int k0 = 0; k0 < 256; k0 += 64) {
#pragma unroll
        for (int p = 0; p < 4; ++p) {          // Bs: 128 wrows x 64 k
            int idx = p * 256 + t, row = idx >> 3, ch = idx & 7;
            short8 v = *reinterpret_cast<const short8*>(w2 + (size_t)row * 256 + k0 + ch * 8);
            int byte = (row << 7) | (ch << 4); byte ^= (row & 7) << 4;
            *reinterpret_cast<short8*>(Bs + byte) = v;
        }
        __syncthreads();
#pragma unroll
        for (int k32 = 0; k32 < 2; ++k32) {
            short8 af[2], bq[4];
#pragma unroll
            for (int m = 0; m < 2; ++m) {
                int row = wr * 32 + m * 16 + lr;
                int byte = (row << 9) | (k0 * 2 + k32 * 64 + lkb); byte ^= (row & 7) << 4;
                af[m] = *reinterpret_cast<const short8*>(Ts + byte);
            }
#pragma unroll
            for (int n = 0; n < 4; ++n) {
                int wrow = wc * 64 + n * 16 + lr;
                int byte = (wrow << 7) | (k32 * 64 + lkb); byte ^= (wrow & 7) << 4;
                bq[n] = *reinterpret_cast<const short8*>(Bs + byte);
            }
#pragma unroll
            for (int m = 0; m < 2; ++m)
#pragma unroll
                for (int n = 0; n < 4; ++n)
                    acu[m][n] = __builtin_amdgcn_mfma_f32_16x16x32_bf16(af[m], bq[n], acu[m][n], 0, 0, 0);
        }
        __syncthreads();
    }
    // epilogue C: store u fp32 + BN partial sums
    if (t < 128) { s1[t] = 0.f; s2[t] = 0.f; }
    __syncthreads();
    {
        float e1[4] = {0.f, 0.f, 0.f, 0.f}, e2[4] = {0.f, 0.f, 0.f, 0.f};
#pragma unroll
        for (int m = 0; m < 2; ++m)
#pragma unroll
            for (int j = 0; j < 4; ++j) {
                int grow = rb + wr * 32 + m * 16 + (lane >> 4) * 4 + j;
                if (grow >= N_NODES) continue;
#pragma unroll
                for (int n = 0; n < 4; ++n) {
                    int col = wc * 64 + n * 16 + lr;
                    float u = fmaxf(acu[m][n][j] + b2[col], 0.f);
                    uf[(size_t)grow * DD + col] = u;
                    e1[n] += u; e2[n] += u * u;
                }
            }
#pragma unroll
        for (int n = 0; n < 4; ++n) {
            int col = wc * 64 + n * 16 + lr;
            atomicAdd(&s1[col], e1[n]);
            atomicAdd(&s2[col], e2[n]);
        }
    }
    __syncthreads();
    if (t < 128) {
        atomicAdd(&bnacc[t], s1[t]);
        atomicAdd(&bnacc[128 + t], s2[t]);
    }
}

__global__ void k_bn_fin(const float* __restrict__ part, int nb, float inv_n,
                         float* __restrict__ mean, float* __restrict__ inv)
{
    int c = threadIdx.x; // 128 threads
    float s1 = 0.f, s2 = 0.f;
    for (int b = 0; b < nb; ++b) {
        s1 += part[(size_t)b * 256 + c];
        s2 += part[(size_t)b * 256 + 128 + c];
    }
    float m = s1 * inv_n;
    float v = s2 * inv_n - m * m;
    mean[c] = m;
    inv[c] = rsqrtf(v + 1e-5f);
}

// ---------- BN apply + h update + hb mirror + colmin(next) + segmented scan into G ----------
__global__ __launch_bounds__(256)
void k_bn_apply_scan(const float* __restrict__ u, float* __restrict__ h,
                     ushort* __restrict__ hb,
                     const float* __restrict__ mean, const float* __restrict__ inv,
                     const float* __restrict__ gam, const float* __restrict__ bet,
                     const int* __restrict__ mem, float* __restrict__ G,
                     unsigned int* __restrict__ cmin_next,
                     int colbase, int nrows)
{
    int t = threadIdx.x;
    int c = t & 127, half = t >> 7;
    int r0 = blockIdx.x * 128;
    int rend = r0 + 128; if (rend > nrows) rend = nrows;
    float mu = mean[c], iv = inv[c], g = gam[c], b = bet[c];
    float accv = 0.f, lmin = INFINITY;
    int curg = -1;
    for (int r = r0 + half; r < rend; r += 2) {
        float z = g * (u[(size_t)r * DD + c] - mu) * iv + b;
        float hn = h[(size_t)r * DD + c] + z;
        h[(size_t)r * DD + c] = hn;
        hb[(size_t)r * DD + c] = f2b(hn);
        lmin = fminf(lmin, hn);
        int gg = mem[r];
        if (gg != curg) {
            if (curg >= 0) atomicAdd(&G[(size_t)curg * CATW + colbase + c], accv);
            curg = gg; accv = 0.f;
        }
        accv += z;
    }
    if (curg >= 0) atomicAdd(&G[(size_t)curg * CATW + colbase + c], accv);
    __shared__ float sm[256];
    sm[t] = lmin;
    __syncthreads();
    if (half == 0) atomicMin(&cmin_next[c], encf(fminf(sm[c], sm[c + 128])));
}

// ---------- segmented scan-add of x (fp32) into G cols [0,128) ----------
__global__ __launch_bounds__(256)
void k_scan_x(const float* __restrict__ x, const int* __restrict__ mem,
              float* __restrict__ G, int nrows)
{
    int t = threadIdx.x;
    int c = t & 127, half = t >> 7;
    int r0 = blockIdx.x * 128;
    int rend = r0 + 128; if (rend > nrows) rend = nrows;
    float accv = 0.f;
    int curg = -1;
    for (int r = r0 + half; r < rend; r += 2) {
        float z = x[(size_t)r * DD + c];
        int gg = mem[r];
        if (gg != curg) {
            if (curg >= 0) atomicAdd(&G[(size_t)curg * CATW + c], accv);
            curg = gg; accv = 0.f;
        }
        accv += z;
    }
    if (curg >= 0) atomicAdd(&G[(size_t)curg * CATW + c], accv);
}

// ---------- BN stats partials from fp32 (readout path) ----------
__global__ __launch_bounds__(256)
void k_bn_part(const float* __restrict__ u, float* __restrict__ part, int nrows)
{
    int t = threadIdx.x;
    int c = t & 127, half = t >> 7;
    int r0 = blockIdx.x * 256;
    int rend = r0 + 256; if (rend > nrows) rend = nrows;
    float s1 = 0.f, s2 = 0.f;
    for (int r = r0 + half; r < rend; r += 2) {
        float v = u[(size_t)r * DD + c];
        s1 += v; s2 += v * v;
    }
    __shared__ float sh1[256], sh2[256];
    sh1[t] = s1; sh2[t] = s2;
    __syncthreads();
    if (half == 0) {
        part[(size_t)blockIdx.x * 256 + c]       = sh1[c] + sh1[c + 128];
        part[(size_t)blockIdx.x * 256 + 128 + c] = sh2[c] + sh2[c + 128];
    }
}

// ---------- readout dense0: (2048x768)@(768x256), 8 rows/block ----------
__global__ __launch_bounds__(256)
void k_read0(const float* __restrict__ G, const float* __restrict__ W,
             const float* __restrict__ b, float* __restrict__ o)
{
    __shared__ float As[8][CATW];
    int t = threadIdx.x;
    int rb = blockIdx.x * 8;
#pragma unroll
    for (int p = 0; p < 6; ++p) {
        int idx = p * 256 + t;         // float4 index; 8*768/4 = 1536
        int r = idx / 192, k4 = idx - r * 192;
        float4 v = *reinterpret_cast<const float4*>(G + (size_t)(rb + r) * CATW + k4 * 4);
        *reinterpret_cast<float4*>(&As[r][k4 * 4]) = v;
    }
    __syncthreads();
    float acc[8] = {0.f, 0.f, 0.f, 0.f, 0.f, 0.f, 0.f, 0.f};
    for (int k = 0; k < CATW; k += 4) {
        float w0 = W[(size_t)(k + 0) * HIDW + t];
        float w1 = W[(size_t)(k + 1) * HIDW + t];
        float w2 = W[(size_t)(k + 2) * HIDW + t];
        float w3 = W[(size_t)(k + 3) * HIDW + t];
#pragma unroll
        for (int r = 0; r < 8; ++r) {
            float4 a = *reinterpret_cast<const float4*>(&As[r][k]);
            acc[r] += a.x * w0 + a.y * w1 + a.z * w2 + a.w * w3;
        }
    }
    float bb = b[t];
#pragma unroll
    for (int r = 0; r < 8; ++r)
        o[(size_t)(rb + r) * HIDW + t] = fmaxf(acc[r] + bb, 0.f);
}

// ---------- readout dense1: (2048x256)@(256x128), 16 rows/block ----------
__global__ __launch_bounds__(256)
void k_read1(const float* __restrict__ A, const float* __restrict__ W,
             const float* __restrict__ b, float* __restrict__ o)
{
    __shared__ float As[16][HIDW];
    int t = threadIdx.x;
    int c = t & 127, rh = t >> 7;      // 2 row-halves x 128 cols
    int rb = blockIdx.x * 16;
#pragma unroll
    for (int p = 0; p < 4; ++p) {
        int idx = p * 256 + t;         // float4 index; 16*256/4 = 1024
        int r = idx >> 6, k4 = idx & 63;
        float4 v = *reinterpret_cast<const float4*>(A + (size_t)(rb + r) * HIDW + k4 * 4);
        *reinterpret_cast<float4*>(&As[r][k4 * 4]) = v;
    }
    __syncthreads();
    float acc[8] = {0.f, 0.f, 0.f, 0.f, 0.f, 0.f, 0.f, 0.f};
    for (int k = 0; k < HIDW; k += 4) {
        float w0 = W[(size_t)(k + 0) * DD + c];
        float w1 = W[(size_t)(k + 1) * DD + c];
        float w2 = W[(size_t)(k + 2) * DD + c];
        float w3 = W[(size_t)(k + 3) * DD + c];
#pragma unroll
        for (int r = 0; r < 8; ++r) {
            float4 a = *reinterpret_cast<const float4*>(&As[rh * 8 + r][k]);
            acc[r] += a.x * w0 + a.y * w1 + a.z * w2 + a.w * w3;
        }
    }
    float bb = b[c];
#pragma unroll
    for (int r = 0; r < 8; ++r)
        o[(size_t)(rb + rh * 8 + r) * DD + c] = fmaxf(acc[r] + bb, 0.f);
}

// ---------- final BN + dot with dense2 ----------
__global__ __launch_bounds__(256)
void k_final(const float* __restrict__ g1, const float* __restrict__ mean,
             const float* __restrict__ inv, const float* __restrict__ gam,
             const float* __restrict__ bet, const float* __restrict__ W2,
             const float* __restrict__ b2, float* __restrict__ out)
{
    int w = threadIdx.x >> 6, lane = threadIdx.x & 63;
    int row = blockIdx.x * 4 + w;
    float s = 0.f;
#pragma unroll
    for (int q = 0; q < 2; ++q) {
        int c = lane + q * 64;
        float v = gam[c] * (g1[(size_t)row * DD + c] - mean[c]) * inv[c] + bet[c];
        s += v * W2[c];
    }
#pragma unroll
    for (int off = 32; off > 0; off >>= 1) s += __shfl_down(s, off);
    if (lane == 0) out[row] = s + b2[0];
}

extern "C" void kernel_launch(void* const* d_in, const int* in_sizes, int n_in,
                              void* d_out, int out_size, void* d_ws, size_t ws_size,
                              hipStream_t stream)
{
    const float* x       = (const float*)d_in[0];
    const int*   nbr     = (const int*)d_in[1];
    const int*   mem     = (const int*)d_in[2];
    const float* merge_W = (const float*)d_in[3];
    const float* merge_b = (const float*)d_in[4];
    const float* lin1_W  = (const float*)d_in[5];
    const float* lin1_b  = (const float*)d_in[6];
    const float* lin2_W  = (const float*)d_in[7];
    const float* lin2_b  = (const float*)d_in[8];
    const float* bn_g    = (const float*)d_in[9];
    const float* bn_b    = (const float*)d_in[10];
    const float* epsv    = (const float*)d_in[11];
    const float* d0W     = (const float*)d_in[12];
    const float* d0b     = (const float*)d_in[13];
    const float* d1W     = (const float*)d_in[14];
    const float* d1b     = (const float*)d_in[15];
    const float* bn0g    = (const float*)d_in[16];
    const float* bn0b    = (const float*)d_in[17];
    const float* d2W     = (const float*)d_in[18];
    const float* d2b     = (const float*)d_in[19];
    float* out = (float*)d_out;

    // ---- workspace carve (256B aligned chunks) ----
    char* p = (char*)d_ws;
    auto alloc = [&](size_t bytes) { char* r = p; p += (bytes + 255) & ~(size_t)255; return r; };
    float*  h     = (float*)alloc((size_t)N_NODES * DD * 4);        // fp32 master h
    ushort* hb    = (ushort*)alloc((size_t)N_NODES * DD * 2);       // bf16 mirror
    ushort* Abuf  = (ushort*)alloc((size_t)N_NODES * 2 * DD * 2);   // aggregation A (N x 256 bf16)
    float*  uf    = (float*)alloc((size_t)N_NODES * DD * 4);        // u (lin2 out, fp32)
    float*  G     = (float*)alloc((size_t)NGRAPH * CATW * 4);
    float*  g0    = (float*)alloc((size_t)NGRAPH * HIDW * 4);
    float*  g1    = (float*)alloc((size_t)NGRAPH * DD * 4);
    float*  part  = (float*)alloc((size_t)391 * 256 * 4);
    float*  red   = (float*)alloc(1024 * 4);
    unsigned int* cminb = (unsigned int*)alloc(6 * DD * 4);         // 6 colmin bufs (enc)
    float*  bnacc = (float*)alloc((size_t)NBLOCKS * 2 * DD * 4);    // per-iter BN sums
    ushort* mergeT = (ushort*)alloc((size_t)NBLOCKS * 2 * DD * DD * 2);
    ushort* lin1T  = (ushort*)alloc((size_t)NBLOCKS * DD * HIDW * 2);
    ushort* lin2T  = (ushort*)alloc((size_t)NBLOCKS * HIDW * DD * 2);
    float* meanp  = red + DD;
    float* invp   = red + 2 * DD;

    const int NBP = 391;      // ceil(100000/256)
    const int NRB = 782;      // ceil(100000/128)
    const int NFB = 1563;     // ceil(100000/64)

    k_init<<<12500, 256, 0, stream>>>(x, h, hb);
    k_setup<<<1, 256, 0, stream>>>(cminb, bnacc);
    {   // weight convert + transpose (fp32 (K,M) -> bf16 (M,K))
        int tm = NBLOCKS * 2 * DD * DD;
        k_convT<<<(tm + 255) / 256, 256, 0, stream>>>(merge_W, mergeT, 2 * DD, DD, tm);
        int t1 = NBLOCKS * DD * HIDW;
        k_convT<<<(t1 + 255) / 256, 256, 0, stream>>>(lin1_W, lin1T, DD, HIDW, t1);
        int t2 = NBLOCKS * HIDW * DD;
        k_convT<<<(t2 + 255) / 256, 256, 0, stream>>>(lin2_W, lin2T, HIDW, DD, t2);
    }
    hipMemsetAsync(G, 0, (size_t)NGRAPH * CATW * sizeof(float), stream);
    k_colmin_part<<<NBP, 256, 0, stream>>>(x, part, N_NODES);
    k_colmin_fin<<<1, 128, 0, stream>>>(part, cminb, NBP);
    k_scan_x<<<NRB, 256, 0, stream>>>(x, mem, G, N_NODES);

    for (int i = 0; i < NBLOCKS; ++i) {
        k_aggregate_b<<<N_NODES / 8, 256, 0, stream>>>(hb, nbr, cminb + (size_t)i * DD, Abuf);
        k_fused_mlp<<<NFB, 256, 0, stream>>>(
            Abuf, h,
            mergeT + (size_t)i * 2 * DD * DD,
            lin1T + (size_t)i * DD * HIDW,
            lin2T + (size_t)i * HIDW * DD,
            merge_b + (size_t)i * DD, lin1_b + (size_t)i * HIDW, lin2_b + (size_t)i * DD,
            epsv + i, uf, bnacc + (size_t)i * 2 * DD);
        k_bn_fin<<<1, 128, 0, stream>>>(bnacc + (size_t)i * 2 * DD, 1, 1.f / (float)N_NODES, meanp, invp);
        k_bn_apply_scan<<<NRB, 256, 0, stream>>>(uf, h, hb, meanp, invp,
                                                 bn_g + (size_t)i * DD, bn_b + (size_t)i * DD,
                                                 mem, G, cminb + (size_t)(i + 1) * DD,
                                                 (i + 1) * DD, N_NODES);
    }

    // readout MLP — fp32, high-parallelism row-strip kernels
    k_read0<<<NGRAPH / 8, 256, 0, stream>>>(G, d0W, d0b, g0);
    k_read1<<<NGRAPH / 16, 256, 0, stream>>>(g0, d1W, d1b, g1);
    k_bn_part<<<8, 256, 0, stream>>>(g1, part, NGRAPH);
    k_bn_fin<<<1, 128, 0, stream>>>(part, 8, 1.f / (float)NGRAPH, meanp, invp);
    k_final<<<NGRAPH / 4, 256, 0, stream>>>(g1, meanp, invp, bn0g, bn0b, d2W, d2b, out);
}